// Round 9
// baseline (120.898 us; speedup 1.0000x reference)
//
#include <hip/hip_runtime.h>
#include <hip/hip_bf16.h>

// BEV pool v2, round 8:
//  prep_convert: feat fp32->bf16 (2.7MB) and depth fp32->bf16 (4MB) tables.
//                Both L2-resident per XCD afterwards.
//  prep_pack:    dpack[p] = {rf[p], (float)depth_bf16[rd[p]]} — random depth
//                probes hit the L2-resident 4MB bf16 table, done exactly once.
//  main:         thread = (interval, split, lane10); lane10 covers 8 channels
//                as one 16B bf16x8 gather; 4-point unroll for MLP; LDS combine
//                across 8 splits; exclusive store (no atomics).

#define C_CH   80
#define NL     10                    // lanes per feat row (8 ch each)
#define SPLITS 8
#define IPB    4
#define BLOCK  (IPB * SPLITS * NL)   // 320

__device__ __forceinline__ unsigned pack_bf16(float2 v) {
    unsigned a = __float_as_uint(v.x);
    unsigned b = __float_as_uint(v.y);
    a = (a + 0x7fffu + ((a >> 16) & 1u)) >> 16;   // RTNE
    b = (b + 0x7fffu + ((b >> 16) & 1u)) >> 16;
    return a | (b << 16);
}

__global__ void prep_convert(const float2* __restrict__ feat2,
                             const float2* __restrict__ depth2,
                             unsigned* __restrict__ fbf,
                             unsigned* __restrict__ dbf,
                             int NF2, int ND2) {
    int i = blockIdx.x * blockDim.x + threadIdx.x;
    if (i < NF2) fbf[i] = pack_bf16(feat2[i]);
    if (i < ND2) dbf[i] = pack_bf16(depth2[i]);
}

__global__ void prep_pack(const unsigned short* __restrict__ dbf,
                          const int* __restrict__ rd,
                          const int* __restrict__ rf,
                          uint2* __restrict__ dpack, int P) {
    int i = blockIdx.x * blockDim.x + threadIdx.x;
    if (i < P) {
        unsigned h = dbf[rd[i]];
        float d = __uint_as_float(h << 16);
        dpack[i] = make_uint2((unsigned)rf[i], __float_as_uint(d));
    }
}

__device__ __forceinline__ void bf8_fma(float acc[8], float d, int4 w) {
    unsigned v[4] = {(unsigned)w.x, (unsigned)w.y, (unsigned)w.z, (unsigned)w.w};
    #pragma unroll
    for (int k = 0; k < 4; ++k) {
        float lo = __uint_as_float(v[k] << 16);
        float hi = __uint_as_float(v[k] & 0xffff0000u);
        acc[2 * k]     += d * lo;
        acc[2 * k + 1] += d * hi;
    }
}

template <bool FAST>
__global__ __launch_bounds__(BLOCK) void bev_main(
    const float*  __restrict__ depth,   // fp32 fallback
    const int*    __restrict__ rd,      // fallback
    const uint2*  __restrict__ dpack,   // {rf, depth} per point
    const int4*   __restrict__ fbf,     // bf16 rows, 10 x 16B granules/row
    const float4* __restrict__ featf,   // fp32 fallback, 20 granules/row
    const int*    __restrict__ rf,      // fallback
    const int*    __restrict__ rb,      // sorted
    const int*    __restrict__ istart,
    const int*    __restrict__ ilen,
    int n_intervals,
    int n_bev,                          // 16384
    float* __restrict__ out)            // [80][n_bev]
{
    __shared__ float red[IPB][SPLITS][NL][9];   // pad 9 to spread banks

    int tid   = threadIdx.x;
    int il    = tid / (SPLITS * NL);
    int r     = tid - il * (SPLITS * NL);
    int split = r / NL;
    int l10   = r - split * NL;          // 0..9
    int interval = blockIdx.x * IPB + il;
    bool valid = interval < n_intervals;

    float acc[8] = {0.f, 0.f, 0.f, 0.f, 0.f, 0.f, 0.f, 0.f};
    int bev = 0;

    if (valid) {
        int start = istart[interval];
        int len   = ilen[interval];
        bev = rb[start];

        int i = split;
        if (FAST) {
            // 4-point unroll: 4 dpack loads + 4 feat gathers in flight.
            for (; i + 3 * SPLITS < len; i += 4 * SPLITS) {
                int p0 = start + i;
                int p1 = p0 + SPLITS;
                int p2 = p0 + 2 * SPLITS;
                int p3 = p0 + 3 * SPLITS;
                uint2 w0 = dpack[p0], w1 = dpack[p1];
                uint2 w2 = dpack[p2], w3 = dpack[p3];
                int4 f0 = fbf[(long)w0.x * NL + l10];
                int4 f1 = fbf[(long)w1.x * NL + l10];
                int4 f2 = fbf[(long)w2.x * NL + l10];
                int4 f3 = fbf[(long)w3.x * NL + l10];
                bf8_fma(acc, __uint_as_float(w0.y), f0);
                bf8_fma(acc, __uint_as_float(w1.y), f1);
                bf8_fma(acc, __uint_as_float(w2.y), f2);
                bf8_fma(acc, __uint_as_float(w3.y), f3);
            }
            for (; i < len; i += SPLITS) {
                int p = start + i;
                uint2 w = dpack[p];
                int4 f = fbf[(long)w.x * NL + l10];
                bf8_fma(acc, __uint_as_float(w.y), f);
            }
        } else {
            for (; i < len; i += SPLITS) {
                int p = start + i;
                float d = depth[rd[p]];
                int q = rf[p];
                float4 a0 = featf[(long)q * 20 + l10 * 2];
                float4 a1 = featf[(long)q * 20 + l10 * 2 + 1];
                acc[0] += d * a0.x; acc[1] += d * a0.y;
                acc[2] += d * a0.z; acc[3] += d * a0.w;
                acc[4] += d * a1.x; acc[5] += d * a1.y;
                acc[6] += d * a1.z; acc[7] += d * a1.w;
            }
        }
    }

    #pragma unroll
    for (int j = 0; j < 8; ++j) red[il][split][l10][j] = acc[j];
    __syncthreads();

    if (valid && split == 0) {
        float s[8];
        #pragma unroll
        for (int j = 0; j < 8; ++j) s[j] = acc[j];
        #pragma unroll
        for (int k = 1; k < SPLITS; ++k) {
            #pragma unroll
            for (int j = 0; j < 8; ++j) s[j] += red[il][k][l10][j];
        }
        long ob = (long)(l10 * 8) * n_bev + bev;
        #pragma unroll
        for (int j = 0; j < 8; ++j) out[ob + (long)j * n_bev] = s[j];
    }
}

extern "C" void kernel_launch(void* const* d_in, const int* in_sizes, int n_in,
                              void* d_out, int out_size, void* d_ws, size_t ws_size,
                              hipStream_t stream) {
    const float*  depth = (const float*)d_in[0];
    const float*  featf = (const float*)d_in[1];
    const int* ranks_depth = (const int*)d_in[2];
    const int* ranks_feat  = (const int*)d_in[3];
    const int* ranks_bev   = (const int*)d_in[4];
    // d_in[5] = bev_feat_shape (static)
    const int* interval_starts  = (const int*)d_in[6];
    const int* interval_lengths = (const int*)d_in[7];

    int P   = in_sizes[2];               // 1,000,000
    int NF  = in_sizes[1];               // 1,351,680 floats (feat)
    int ND  = in_sizes[0];               // 1,993,728 floats (depth)
    int NF2 = NF / 2, ND2 = ND / 2;
    int n_intervals = in_sizes[6];
    int n_bev = out_size / C_CH;         // 16384
    float* out = (float*)d_out;

    // ws layout: dpack (P*8B) | fbf (NF*2B) | dbf (ND*2B), 16B-aligned blocks.
    size_t dpack_bytes = ((size_t)P * 8 + 15) & ~(size_t)15;
    size_t fbf_bytes   = ((size_t)NF * 2 + 15) & ~(size_t)15;
    size_t dbf_bytes   = (size_t)ND * 2;
    bool fast = ws_size >= dpack_bytes + fbf_bytes + dbf_bytes;

    uint2*    dpack = (uint2*)d_ws;
    unsigned* fbf   = (unsigned*)((char*)d_ws + dpack_bytes);
    unsigned* dbf   = (unsigned*)((char*)d_ws + dpack_bytes + fbf_bytes);

    // Zero output: uncovered BEV cells must read 0 (harness poisons 0xAA).
    hipMemsetAsync(d_out, 0, (size_t)out_size * sizeof(float), stream);

    if (fast) {
        int n1 = (NF2 > ND2 ? NF2 : ND2);
        prep_convert<<<(n1 + 255) / 256, 256, 0, stream>>>(
            (const float2*)featf, (const float2*)depth, fbf, dbf, NF2, ND2);
        prep_pack<<<(P + 255) / 256, 256, 0, stream>>>(
            (const unsigned short*)dbf, ranks_depth, ranks_feat, dpack, P);
    }

    int grid = (n_intervals + IPB - 1) / IPB;
    if (fast) {
        bev_main<true><<<grid, BLOCK, 0, stream>>>(
            depth, ranks_depth, dpack, (const int4*)fbf, (const float4*)featf,
            ranks_feat, ranks_bev, interval_starts, interval_lengths,
            n_intervals, n_bev, out);
    } else {
        bev_main<false><<<grid, BLOCK, 0, stream>>>(
            depth, ranks_depth, dpack, (const int4*)fbf, (const float4*)featf,
            ranks_feat, ranks_bev, interval_starts, interval_lengths,
            n_intervals, n_bev, out);
    }
}

// Round 10
// 119.842 us; speedup vs baseline: 1.0088x; 1.0088x over previous
//
#include <hip/hip_runtime.h>
#include <hip/hip_bf16.h>

// BEV pool v2, round 10:
//  prep: feat fp32 -> bf16 rows (2.7MB, L2-resident everywhere). One pass.
//  main: block = 4 contiguous intervals = contiguous point range [s0, s0+L).
//        Stage phase: 320 threads cooperatively load rd/rf (coalesced) and
//        probe fp32 depth ONCE per point -> LDS {rf, d} pairs.
//        Accum phase: thread (il, split, l10) reads pairs from LDS
//        (broadcast, conflict-free) and gathers 16B bf16x8 feat granules.
//        LDS combine over 8 splits, exclusive store (no atomics).

#define C_CH   80
#define NL     10                    // lanes per feat row (8 ch each)
#define SPLITS 8
#define IPB    4
#define BLOCK  (IPB * SPLITS * NL)   // 320
#define CAP    1024                  // staged points per block (λ=61*4 « CAP)

__device__ __forceinline__ unsigned pack_bf16(float2 v) {
    unsigned a = __float_as_uint(v.x);
    unsigned b = __float_as_uint(v.y);
    a = (a + 0x7fffu + ((a >> 16) & 1u)) >> 16;   // RTNE
    b = (b + 0x7fffu + ((b >> 16) & 1u)) >> 16;
    return a | (b << 16);
}

__global__ void prep_feat(const float2* __restrict__ feat2,
                          unsigned* __restrict__ fbf, int NF2) {
    int i = blockIdx.x * blockDim.x + threadIdx.x;
    if (i < NF2) fbf[i] = pack_bf16(feat2[i]);
}

__device__ __forceinline__ void bf8_fma(float acc[8], float d, int4 w) {
    unsigned v[4] = {(unsigned)w.x, (unsigned)w.y, (unsigned)w.z, (unsigned)w.w};
    #pragma unroll
    for (int k = 0; k < 4; ++k) {
        float lo = __uint_as_float(v[k] << 16);
        float hi = __uint_as_float(v[k] & 0xffff0000u);
        acc[2 * k]     += d * lo;
        acc[2 * k + 1] += d * hi;
    }
}

template <bool FAST>
__global__ __launch_bounds__(BLOCK) void bev_main(
    const float*  __restrict__ depth,
    const int*    __restrict__ rd,
    const int4*   __restrict__ fbf,     // bf16 rows, 10 x 16B granules/row
    const float4* __restrict__ featf,   // fp32 fallback, 20 granules/row
    const int*    __restrict__ rf,
    const int*    __restrict__ rb,      // sorted
    const int*    __restrict__ istart,
    const int*    __restrict__ ilen,
    int n_intervals,
    int n_bev,                          // 16384
    float* __restrict__ out)            // [80][n_bev]
{
    __shared__ uint2 pairs[CAP];                 // {rf, depth_bits} per point
    __shared__ float red[IPB][SPLITS][NL][9];    // pad 9 to spread banks

    int tid   = threadIdx.x;
    int il    = tid / (SPLITS * NL);
    int r     = tid - il * (SPLITS * NL);
    int split = r / NL;
    int l10   = r - split * NL;          // 0..9
    int ibase = blockIdx.x * IPB;
    int interval = ibase + il;
    bool valid = interval < n_intervals;

    // Block's contiguous point range (intervals are contiguous runs).
    int ilast = min(ibase + IPB, n_intervals) - 1;
    int s0 = istart[ibase];
    int L  = istart[ilast] + ilen[ilast] - s0;
    bool use_lds = FAST && (L <= CAP);

    if (use_lds) {
        for (int j = tid; j < L; j += BLOCK) {
            int p = s0 + j;
            float d = depth[rd[p]];
            pairs[j] = make_uint2((unsigned)rf[p], __float_as_uint(d));
        }
    }
    __syncthreads();

    float acc[8] = {0.f, 0.f, 0.f, 0.f, 0.f, 0.f, 0.f, 0.f};
    int bev = 0;

    if (valid) {
        int start = istart[interval];
        int len   = ilen[interval];
        bev = rb[start];
        int base = start - s0;

        int i = split;
        if (use_lds) {
            for (; i + 3 * SPLITS < len; i += 4 * SPLITS) {
                uint2 w0 = pairs[base + i];
                uint2 w1 = pairs[base + i + SPLITS];
                uint2 w2 = pairs[base + i + 2 * SPLITS];
                uint2 w3 = pairs[base + i + 3 * SPLITS];
                int4 f0 = fbf[(long)w0.x * NL + l10];
                int4 f1 = fbf[(long)w1.x * NL + l10];
                int4 f2 = fbf[(long)w2.x * NL + l10];
                int4 f3 = fbf[(long)w3.x * NL + l10];
                bf8_fma(acc, __uint_as_float(w0.y), f0);
                bf8_fma(acc, __uint_as_float(w1.y), f1);
                bf8_fma(acc, __uint_as_float(w2.y), f2);
                bf8_fma(acc, __uint_as_float(w3.y), f3);
            }
            for (; i < len; i += SPLITS) {
                uint2 w = pairs[base + i];
                int4 f = fbf[(long)w.x * NL + l10];
                bf8_fma(acc, __uint_as_float(w.y), f);
            }
        } else if (FAST) {
            for (; i < len; i += SPLITS) {
                int p = start + i;
                float d = depth[rd[p]];
                int4 f = fbf[(long)rf[p] * NL + l10];
                bf8_fma(acc, d, f);
            }
        } else {
            for (; i < len; i += SPLITS) {
                int p = start + i;
                float d = depth[rd[p]];
                int q = rf[p];
                float4 a0 = featf[(long)q * 20 + l10 * 2];
                float4 a1 = featf[(long)q * 20 + l10 * 2 + 1];
                acc[0] += d * a0.x; acc[1] += d * a0.y;
                acc[2] += d * a0.z; acc[3] += d * a0.w;
                acc[4] += d * a1.x; acc[5] += d * a1.y;
                acc[6] += d * a1.z; acc[7] += d * a1.w;
            }
        }
    }

    #pragma unroll
    for (int j = 0; j < 8; ++j) red[il][split][l10][j] = acc[j];
    __syncthreads();

    if (valid && split == 0) {
        float s[8];
        #pragma unroll
        for (int j = 0; j < 8; ++j) s[j] = acc[j];
        #pragma unroll
        for (int k = 1; k < SPLITS; ++k) {
            #pragma unroll
            for (int j = 0; j < 8; ++j) s[j] += red[il][k][l10][j];
        }
        long ob = (long)(l10 * 8) * n_bev + bev;
        #pragma unroll
        for (int j = 0; j < 8; ++j) out[ob + (long)j * n_bev] = s[j];
    }
}

extern "C" void kernel_launch(void* const* d_in, const int* in_sizes, int n_in,
                              void* d_out, int out_size, void* d_ws, size_t ws_size,
                              hipStream_t stream) {
    const float* depth = (const float*)d_in[0];
    const float* featf = (const float*)d_in[1];
    const int* ranks_depth = (const int*)d_in[2];
    const int* ranks_feat  = (const int*)d_in[3];
    const int* ranks_bev   = (const int*)d_in[4];
    // d_in[5] = bev_feat_shape (static)
    const int* interval_starts  = (const int*)d_in[6];
    const int* interval_lengths = (const int*)d_in[7];

    int NF  = in_sizes[1];               // 1,351,680 floats (feat)
    int NF2 = NF / 2;
    int n_intervals = in_sizes[6];
    int n_bev = out_size / C_CH;         // 16384
    float* out = (float*)d_out;

    bool fast = ws_size >= (size_t)NF * 2;
    unsigned* fbf = (unsigned*)d_ws;

    // Zero output: uncovered BEV cells must read 0 (harness poisons 0xAA).
    hipMemsetAsync(d_out, 0, (size_t)out_size * sizeof(float), stream);

    if (fast) {
        prep_feat<<<(NF2 + 255) / 256, 256, 0, stream>>>(
            (const float2*)featf, fbf, NF2);
    }

    int grid = (n_intervals + IPB - 1) / IPB;
    if (fast) {
        bev_main<true><<<grid, BLOCK, 0, stream>>>(
            depth, ranks_depth, (const int4*)fbf, (const float4*)featf,
            ranks_feat, ranks_bev, interval_starts, interval_lengths,
            n_intervals, n_bev, out);
    } else {
        bev_main<false><<<grid, BLOCK, 0, stream>>>(
            depth, ranks_depth, (const int4*)fbf, (const float4*)featf,
            ranks_feat, ranks_bev, interval_starts, interval_lengths,
            n_intervals, n_bev, out);
    }
}